// Round 11
// baseline (2219.458 us; speedup 1.0000x reference)
//
#include <hip/hip_runtime.h>
#include <stdint.h>
#include <math.h>

// Match numpy's non-fused multiply-add rounding: a wrong argmin or a boundary
// mask flip cascades into O(1) output error. R1-R10 passed with absmax 0.0
// using exactly these expression forms — keep them everywhere.
#pragma clang fp contract(off)

#define BLOCK 1024
#define NW (BLOCK / 64)
#define PT 4                 // points/thread/step in full passes (slab-major; fits 64 VGPR)
#define PB 4                 // entries/thread/step in block near-engine
#define MAX_ITERS 50
#define NEAR_CAP 9472        // LDS SoA capacity
#define SOLO_CAP 2048        // below this, wave 0 runs alone
#define HB 32768             // d2 histogram bins = f32 bits >> 17 (15-bit key)
#define HSH 17
#define BPT (HB / BLOCK)     // 32 bins/thread
#define WARR_MAX 32768       // stored d2-prefix entries per block (ws)
#define WALK_TGT 2048        // refill collection target
#define EPS_NORM 1e-8f
#define EPS_SEP (-1e-6f)
#define CMD_REFILL 1
#define CMD_EXIT 2
#define ST_ALIVE 0
#define ST_DEAD 1
#define ST_DONE 2

// R11: monotone d2-walk refills. R10 post-mortem: far targets drain the near
// set in a few cuts (each plane shaves the cap where the near set lives) and
// pay 10-15 full-N 2-pass rebuilds testing all k planes -> ~100k insts/wave.
// Theorem: the closest-survivor sequence is monotone in (d2,idx) — points
// with d2 below the current argmin are already dead. So: at the initial build
// write a d2-bucket-major prefix of indices to ws; refills WALK it from a
// watermark, testing candidates against the plane list once ever. Fallback
// (floor-skipped full build) + escape (argmin-only iterations) cover walk
// exhaustion / hot-bucket cases exactly. HB 4096->32768 (finer threshold,
// 8x less atomic contention), aliased over the SoA.
__global__ __launch_bounds__(BLOCK)
__attribute__((amdgpu_waves_per_eu(4, 4)))
void convex_plane_kernel(
    const float* __restrict__ pc, const float* __restrict__ tg,
    float* __restrict__ out, int N, int M, int stepsA,
    int* __restrict__ wsAll, int WARR)
{
    extern __shared__ uint32_t smem[];
    const int tid  = threadIdx.x;
    const int lane = tid & 63;
    const int wv   = tid >> 6;
    const int m    = blockIdx.x;

    float* sx     = (float*)smem;                 // [NEAR_CAP]
    float* sy     = sx + NEAR_CAP;                // [NEAR_CAP]
    float* sz     = sy + NEAR_CAP;                // [NEAR_CAP]
    int*   sid    = (int*)(sz + NEAR_CAP);        // [NEAR_CAP]
    float* planes = (float*)(sid + NEAR_CAP);     // [52*4] padded, 16B-aligned
    float* red_d  = planes + 52 * 4;              // [NW]
    float* red_x  = red_d + NW;                   // [NW]
    float* red_y  = red_x + NW;                   // [NW]
    float* red_z  = red_y + NW;                   // [NW]
    int*   red_i  = (int*)(red_z + NW);           // [NW]
    int*   wsum   = red_i + NW;                   // [NW]
    int*   ibc    = wsum + NW;                    // [12] see below
    float* fbc    = (float*)(ibc + 12);           // [3] argmin coords
    int*   cur    = (int*)(fbc + 3);              // [1] append cursor
    int*   hist   = (int*)sx;                     // [HB] aliases SoA in builds
    const float4* pl4 = (const float4*)planes;
    // ibc: 0=argIdx 1=ncount 2=Kthr 3=cmd 4=total 5=k 6=wm 7=(unused)
    //      8=KB0 9=base0 10=KNI 11=(unused)

    int* ofsW = wsAll + (size_t)m * (size_t)(HB + WARR);  // [HB] prefix/cursors
    int* idxW = ofsW + HB;                                // [WARR] stored idx

    const float tx = tg[3*m+0], ty = tg[3*m+1], tz = tg[3*m+2];
    const float t2 = tx*tx + ty*ty + tz*tz;

    float* out_a = out;
    float* out_b = out + (size_t)MAX_ITERS * (size_t)M * 3;

    // pad planes: {0,0,0,+inf} never separates (dt=-inf < EPS_SEP) — lets all
    // plane loops run in register chunks of 4.
    if (tid < 52) {
        planes[4*tid+0] = 0.f; planes[4*tid+1] = 0.f;
        planes[4*tid+2] = 0.f; planes[4*tid+3] = INFINITY;
    }

    // block-wide lexicographic (d2,idx) argmin + coords + total; ncount=cur[0].
    auto finishC = [&](float dmin, int imin, float mx, float my, float mz,
                       int mycnt) {
        #pragma unroll
        for (int off = 32; off > 0; off >>= 1) {
            float od = __shfl_down(dmin, off, 64);
            int   oi = __shfl_down(imin, off, 64);
            float ox = __shfl_down(mx, off, 64);
            float oy = __shfl_down(my, off, 64);
            float oz = __shfl_down(mz, off, 64);
            int   oc = __shfl_down(mycnt, off, 64);
            if (od < dmin || (od == dmin && oi < imin)) {
                dmin = od; imin = oi; mx = ox; my = oy; mz = oz;
            }
            mycnt += oc;
        }
        if (lane == 0) {
            red_d[wv] = dmin; red_i[wv] = imin;
            red_x[wv] = mx; red_y[wv] = my; red_z[wv] = mz; wsum[wv] = mycnt;
        }
        __syncthreads();
        if (wv == 0) {
            float bd = (lane < NW) ? red_d[lane] : INFINITY;
            int   bi = (lane < NW) ? red_i[lane] : 0;
            float bx = (lane < NW) ? red_x[lane] : 0.f;
            float by = (lane < NW) ? red_y[lane] : 0.f;
            float bz = (lane < NW) ? red_z[lane] : 0.f;
            int   c  = (lane < NW) ? wsum[lane]  : 0;
            #pragma unroll
            for (int off = 8; off > 0; off >>= 1) {
                float od = __shfl_down(bd, off, 64);
                int   oi = __shfl_down(bi, off, 64);
                float ox = __shfl_down(bx, off, 64);
                float oy = __shfl_down(by, off, 64);
                float oz = __shfl_down(bz, off, 64);
                int   oc = __shfl_down(c, off, 64);
                if (od < bd || (od == bd && oi < bi)) {
                    bd = od; bi = oi; bx = ox; by = oy; bz = oz;
                }
                c += oc;
            }
            if (lane == 0) {
                ibc[0] = bi; ibc[1] = cur[0]; ibc[4] = c;
                fbc[0] = bx; fbc[1] = by; fbc[2] = bz;
            }
        }
        __syncthreads();
    };

    // Full build: pass A histograms d2-keys of survivors (key>=keyFloor only —
    // below-floor are known dead); threshold at capLimit -> Kthr; writePrefix
    // also computes KB0/base0 and scatters [Kthr,KB0) indices to ws. Pass B
    // collects near (key<Kthr) into SoA + exact argmin/total over ALL survivors.
    auto buildNear = [&](int kplanes, int keyFloor, bool writePrefix,
                         int capLimit) {
        for (int h = tid; h < HB; h += BLOCK) hist[h] = 0;
        __syncthreads();
        // ---- pass A ----
        for (int s = 0; s < stepsA; ++s) {
            const int ib = s * PT * BLOCK + tid;
            uint32_t live = 0;
            float px[PT], py[PT], pz[PT];
            int keyv[PT];
            #pragma unroll
            for (int j = 0; j < PT; ++j) {
                const int i = ib + j * BLOCK;
                if (i < N) {
                    live |= (1u << j);
                    const float* p = pc + 3 * (size_t)i;
                    px[j] = p[0]; py[j] = p[1]; pz[j] = p[2];
                }
            }
            #pragma unroll
            for (int j = 0; j < PT; ++j) if ((live >> j) & 1u) {
                float p2 = px[j]*px[j] + py[j]*py[j] + pz[j]*pz[j];
                float tp = tx*px[j] + ty*py[j] + tz*pz[j];
                float d2 = t2 + p2 - 2.0f*tp;        // reference's exact form
                keyv[j] = (int)(__float_as_uint(d2) >> HSH);
                if (keyv[j] < keyFloor) live &= ~(1u << j);   // known dead
            }
            for (int q0 = 0; q0 < kplanes && live; q0 += 4) {
                float4 a0 = pl4[q0], a1 = pl4[q0+1], a2 = pl4[q0+2], a3 = pl4[q0+3];
                #pragma unroll
                for (int j = 0; j < PT; ++j) if ((live >> j) & 1u) {
                    float d0 = a0.x*px[j] + a0.y*py[j] + a0.z*pz[j] - a0.w;
                    float d1 = a1.x*px[j] + a1.y*py[j] + a1.z*pz[j] - a1.w;
                    float d2t = a2.x*px[j] + a2.y*py[j] + a2.z*pz[j] - a2.w;
                    float d3 = a3.x*px[j] + a3.y*py[j] + a3.z*pz[j] - a3.w;
                    if (d0 >= EPS_SEP || d1 >= EPS_SEP || d2t >= EPS_SEP || d3 >= EPS_SEP)
                        live &= ~(1u << j);
                }
            }
            #pragma unroll
            for (int j = 0; j < PT; ++j) if ((live >> j) & 1u)
                atomicAdd(&hist[keyv[j]], 1);
        }
        __syncthreads();
        // ---- threshold ----
        const int b0 = tid * BPT;
        int ls = 0;
        for (int u = 0; u < BPT; ++u) ls += hist[b0 + u];
        int incl = ls;
        #pragma unroll
        for (int off = 1; off < 64; off <<= 1) {
            int o = __shfl_up(incl, off, 64);
            if (lane >= off) incl += o;
        }
        if (lane == 63) wsum[wv] = incl;
        if (tid == 0) { ibc[2] = HB; if (writePrefix) ibc[8] = HB; }
        __syncthreads();
        if (wv == 0 && lane < NW) {
            int v = wsum[lane];
            int i2 = v;
            #pragma unroll
            for (int off = 1; off < NW; off <<= 1) {
                int o = __shfl_up(i2, off, 64);
                if (lane >= off) i2 += o;
            }
            wsum[lane] = i2 - v;                     // exclusive wave base
        }
        __syncthreads();
        const int ex = wsum[wv] + incl - ls;         // excl prefix before b0
        if (tid == BLOCK - 1) ibc[4] = ex + ls;      // total survivors
        {   // crossing 1: Kthr (largest prefix <= capLimit); exactly one hit
            int c = ex;
            for (int u = 0; u < BPT; ++u) {
                const int hv = hist[b0 + u];
                if (c <= capLimit && c + hv > capLimit) {
                    ibc[2] = b0 + u;
                    if (writePrefix) ibc[9] = c;     // base0 = prefix(Kthr)
                }
                c += hv;
            }
        }
        __syncthreads();
        if (writePrefix) {
            if (tid == 0 && ibc[2] == HB) ibc[9] = ibc[4];  // all near
            __syncthreads();
            const int T2 = ibc[9] + WARR;            // stored positions < WARR
            int c = ex;
            for (int u = 0; u < BPT; ++u) {
                const int hv = hist[b0 + u];
                if (c <= T2 && c + hv > T2) ibc[8] = b0 + u;
                ofsW[b0 + u] = c;                    // exclusive prefix to ws
                c += hv;
            }
            __syncthreads();
        }
        const int Kthr   = ibc[2];
        const int KB0w   = writePrefix ? ibc[8] : HB;
        const int base0w = writePrefix ? ibc[9] : 0;
        if (tid == 0) cur[0] = 0;
        __syncthreads();                             // hist (sx) dead after this
        if (ibc[4] == 0) {                           // no survivors at all
            if (tid == 0) ibc[1] = 0;
            __syncthreads();
            return;
        }
        // ---- pass B ----
        float dmin = INFINITY; int imin = 0;
        float mx = 0.f, my = 0.f, mz = 0.f;
        int mycnt = 0;
        for (int s = 0; s < stepsA; ++s) {
            const int ib = s * PT * BLOCK + tid;
            uint32_t live = 0;
            float px[PT], py[PT], pz[PT], d2v[PT];
            #pragma unroll
            for (int j = 0; j < PT; ++j) {
                const int i = ib + j * BLOCK;
                if (i < N) {
                    live |= (1u << j);
                    const float* p = pc + 3 * (size_t)i;
                    px[j] = p[0]; py[j] = p[1]; pz[j] = p[2];
                }
            }
            #pragma unroll
            for (int j = 0; j < PT; ++j) if ((live >> j) & 1u) {
                float p2 = px[j]*px[j] + py[j]*py[j] + pz[j]*pz[j];
                float tp = tx*px[j] + ty*py[j] + tz*pz[j];
                d2v[j] = t2 + p2 - 2.0f*tp;          // bitwise same as pass A
                if ((int)(__float_as_uint(d2v[j]) >> HSH) < keyFloor)
                    live &= ~(1u << j);
            }
            for (int q0 = 0; q0 < kplanes && live; q0 += 4) {
                float4 a0 = pl4[q0], a1 = pl4[q0+1], a2 = pl4[q0+2], a3 = pl4[q0+3];
                #pragma unroll
                for (int j = 0; j < PT; ++j) if ((live >> j) & 1u) {
                    float d0 = a0.x*px[j] + a0.y*py[j] + a0.z*pz[j] - a0.w;
                    float d1 = a1.x*px[j] + a1.y*py[j] + a1.z*pz[j] - a1.w;
                    float d2t = a2.x*px[j] + a2.y*py[j] + a2.z*pz[j] - a2.w;
                    float d3 = a3.x*px[j] + a3.y*py[j] + a3.z*pz[j] - a3.w;
                    if (d0 >= EPS_SEP || d1 >= EPS_SEP || d2t >= EPS_SEP || d3 >= EPS_SEP)
                        live &= ~(1u << j);
                }
            }
            mycnt += (int)__popc(live);
            #pragma unroll
            for (int j = 0; j < PT; ++j) {
                bool nearkeep = false;
                if ((live >> j) & 1u) {
                    const int i = ib + j * BLOCK;
                    const float d2j = d2v[j];
                    if (d2j < dmin || (d2j == dmin && i < imin)) {
                        dmin = d2j; imin = i; mx = px[j]; my = py[j]; mz = pz[j];
                    }
                    const int keyj = (int)(__float_as_uint(d2j) >> HSH);
                    nearkeep = (keyj < Kthr);
                    if (writePrefix && !nearkeep && keyj < KB0w) {
                        int pos = atomicAdd(&ofsW[keyj], 1) - base0w; // ofs->post
                        idxW[pos] = i;
                    }
                }
                unsigned long long bal = __ballot(nearkeep);
                if (bal) {
                    int base = 0;
                    if (lane == 0) base = atomicAdd(cur, (int)__popcll(bal));
                    base = __shfl(base, 0, 64);
                    if (nearkeep) {
                        int pos = base + (int)__popcll(bal & ((1ull << lane) - 1ull));
                        sx[pos] = px[j]; sy[pos] = py[j]; sz[pos] = pz[j];
                        sid[pos] = ib + j * BLOCK;
                    }
                }
            }
        }
        finishC(dmin, imin, mx, my, mz, mycnt);
    };

    // Block near-engine: cut SoA in place (proven discipline).
    auto scanN = [&](int count, float ax, float ay, float az, float b) {
        if (tid == 0) cur[0] = 0;
        __syncthreads();
        float dmin = INFINITY; int imin = 0;
        float mx = 0.f, my = 0.f, mz = 0.f;
        const int per = BLOCK * PB;
        const int bsteps = (count + per - 1) / per;
        for (int s = 0; s < bsteps; ++s) {
            float X[PB], Y[PB], Z[PB], D[PB]; int J[PB];
            uint32_t keepm = 0;
            #pragma unroll
            for (int q = 0; q < PB; ++q) {
                const int e = s * per + q * BLOCK + tid;  // lane-stride 1
                if (e < count) {
                    float px = sx[e], py = sy[e], pz = sz[e];
                    X[q] = px; Y[q] = py; Z[q] = pz; J[q] = sid[e];
                    float dt = ax*px + ay*py + az*pz - b;
                    if (dt < EPS_SEP) {
                        keepm |= (1u << q);
                        float p2 = px*px + py*py + pz*pz;
                        float tp = tx*px + ty*py + tz*pz;
                        D[q] = t2 + p2 - 2.0f*tp;
                    }
                }
            }
            __syncthreads();                         // reads before appends
            int c = (int)__popc(keepm);
            int incl = c;
            #pragma unroll
            for (int off = 1; off < 64; off <<= 1) {
                int o = __shfl_up(incl, off, 64);
                if (lane >= off) incl += o;
            }
            const int excl = incl - c;
            const int tot  = __shfl(incl, 63, 64);
            int wb = 0;
            if (lane == 0) wb = atomicAdd(cur, tot);
            wb = __shfl(wb, 0, 64);
            int pos = wb + excl;
            #pragma unroll
            for (int q = 0; q < PB; ++q) if ((keepm >> q) & 1u) {
                sx[pos] = X[q]; sy[pos] = Y[q]; sz[pos] = Z[q]; sid[pos] = J[q];
                if (D[q] < dmin || (D[q] == dmin && J[q] < imin)) {
                    dmin = D[q]; imin = J[q]; mx = X[q]; my = Y[q]; mz = Z[q];
                }
                ++pos;
            }
        }
        finishC(dmin, imin, mx, my, mz, 0);
    };

    // Block-cooperative refill: walk the stored d2-prefix from the watermark,
    // testing candidates against all planes once; else fallback builds /
    // escape iterations. Returns ST_*; callers read ibc[1]/[5]/fbc after.
    auto refillAll = [&](int capLimit) -> int {
        int k = ibc[5];
        // ---- walk era ----
        if (WARR > 0 && ibc[6] < ibc[8]) {
            int wm = ibc[6];
            const int KB0 = ibc[8], base0 = ibc[9], KNI = ibc[10];
            if (tid == 0) cur[0] = 0;
            __syncthreads();
            float dmin = INFINITY; int imin = 0;
            float mx = 0.f, my = 0.f, mz = 0.f;
            int curNow = 0;
            bool needFall = false;
            while (wm < KB0) {
                int we = ((wm >> 6) + 1) << 6;
                if (we > KB0) we = KB0;
                // post-scatter ofsW[b] = orig prefix of b+1 for stored buckets
                const int s0 = (wm == KNI) ? base0 : ofsW[wm - 1];
                const int s1 = ofsW[we - 1];
                const int cnt = s1 - s0;
                if (curNow + cnt > NEAR_CAP) {       // can't guarantee fit
                    if (curNow == 0) needFall = true;
                    break;
                }
                for (int e0 = s0; e0 < s1; e0 += BLOCK) {
                    const int e = e0 + tid;
                    bool alive = false; int j = 0;
                    float X = 0.f, Y = 0.f, Z = 0.f, D = 0.f;
                    if (e < s1) {
                        j = idxW[e - base0];
                        const float* p = pc + 3 * (size_t)j;
                        X = p[0]; Y = p[1]; Z = p[2];
                        alive = true;
                        for (int q0 = 0; q0 < k && alive; q0 += 4) {
                            float4 a0 = pl4[q0], a1 = pl4[q0+1];
                            float4 a2 = pl4[q0+2], a3 = pl4[q0+3];
                            float d0 = a0.x*X + a0.y*Y + a0.z*Z - a0.w;
                            float d1 = a1.x*X + a1.y*Y + a1.z*Z - a1.w;
                            float d2t = a2.x*X + a2.y*Y + a2.z*Z - a2.w;
                            float d3 = a3.x*X + a3.y*Y + a3.z*Z - a3.w;
                            if (d0 >= EPS_SEP || d1 >= EPS_SEP ||
                                d2t >= EPS_SEP || d3 >= EPS_SEP) alive = false;
                        }
                        if (alive) {
                            float p2 = X*X + Y*Y + Z*Z;
                            float tp = tx*X + ty*Y + tz*Z;
                            D = t2 + p2 - 2.0f*tp;
                        }
                    }
                    unsigned long long bal = __ballot(alive);
                    if (bal) {
                        int base = 0;
                        if (lane == 0) base = atomicAdd(cur, (int)__popcll(bal));
                        base = __shfl(base, 0, 64);
                        if (alive) {
                            int pos = base + (int)__popcll(bal & ((1ull << lane) - 1ull));
                            sx[pos] = X; sy[pos] = Y; sz[pos] = Z; sid[pos] = j;
                            if (D < dmin || (D == dmin && j < imin)) {
                                dmin = D; imin = j; mx = X; my = Y; mz = Z;
                            }
                        }
                    }
                }
                wm = we;
                if (cnt > 0) {
                    __syncthreads();
                    curNow = cur[0];
                    if (curNow >= WALK_TGT) break;
                }
            }
            if (tid == 0) ibc[6] = wm;
            if (!needFall) {
                finishC(dmin, imin, mx, my, mz, 0);  // also orders ibc[6]
                if (ibc[1] > 0) return ST_ALIVE;
                // walk exhausted with nothing -> fallback
            } else {
                __syncthreads();                     // publish ibc[6]
            }
        }
        // ---- fallback / escape era ----
        for (;;) {
            const int fl = (WARR > 0) ? ibc[6] : ibc[6];  // keys < wm all dead
            buildNear(k, fl, false, capLimit);
            if (ibc[4] == 0) {                       // truly empty: pc[0] tail
                const float c0 = pc[0], c1 = pc[1], c2 = pc[2];
                const float vx = c0 - tx, vy = c1 - ty, vz = c2 - tz;
                const float nrm = sqrtf(vx*vx + vy*vy + vz*vz);
                const float den = nrm + EPS_NORM;
                const float ax = vx / den, ay = vy / den, az = vz / den;
                const float b  = ax*c0 + ay*c1 + az*c2;
                for (int q = tid; q < MAX_ITERS - k; q += BLOCK) {
                    const int kk = k + q;
                    const size_t oa = ((size_t)kk * M + m) * 3;
                    out_a[oa+0] = ax; out_a[oa+1] = ay; out_a[oa+2] = az;
                    out_b[(size_t)kk * M + m] = b;
                }
                return ST_DEAD;
            }
            if (ibc[1] > 0) {
                if (tid == 0) ibc[6] = ibc[2];       // keys < Kthr now accounted
                __syncthreads();
                return ST_ALIVE;
            }
            // escape: one hot bucket holds >capLimit survivors. Emit the plane
            // from the EXACT argmin (computed over all survivors) and rebuild.
            const float ccx = fbc[0], ccy = fbc[1], ccz = fbc[2];
            const float vx = ccx - tx, vy = ccy - ty, vz = ccz - tz;
            const float nrm = sqrtf(vx*vx + vy*vy + vz*vz);
            const float den = nrm + EPS_NORM;
            const float ax = vx / den, ay = vy / den, az = vz / den;
            const float b  = ax*ccx + ay*ccy + az*ccz;
            if (tid == 0) {
                const size_t oa = ((size_t)k * M + m) * 3;
                out_a[oa+0] = ax; out_a[oa+1] = ay; out_a[oa+2] = az;
                out_b[(size_t)k * M + m] = b;
                planes[4*k+0] = ax; planes[4*k+1] = ay;
                planes[4*k+2] = az; planes[4*k+3] = b;
            }
            ++k;
            if (tid == 0) ibc[5] = k;
            if (k == MAX_ITERS) { __syncthreads(); return ST_DONE; }
            // loop: buildNear's hist-zero barrier publishes planes/ibc[5]
        }
    };

    // ---- initial build ----
    buildNear(0, 0, WARR > 0, NEAR_CAP);
    if (tid == 0) {
        ibc[10] = ibc[2];                            // KNI (prefix start bucket)
        ibc[6]  = ibc[2];                            // watermark
        if (WARR == 0) { ibc[8] = ibc[2]; ibc[9] = 0; }
        ibc[5] = 0;
        ibc[3] = 0;
    }
    __syncthreads();
    int ncount = ibc[1];
    float ccx = fbc[0], ccy = fbc[1], ccz = fbc[2];
    int k = 0;

    // ---- BLOCK mode ----
    for (;;) {
        if (ncount == 0) {
            if (tid == 0) ibc[5] = k;
            __syncthreads();
            int st = refillAll(NEAR_CAP);
            if (st != ST_ALIVE) return;              // tail written inside if DEAD
            k = ibc[5]; ncount = ibc[1];
            ccx = fbc[0]; ccy = fbc[1]; ccz = fbc[2];
        }
        if (ncount <= SOLO_CAP) break;               // -> solo (ncount > 0)
        const float vx = ccx - tx, vy = ccy - ty, vz = ccz - tz;
        const float nrm = sqrtf(vx*vx + vy*vy + vz*vz);
        const float den = nrm + EPS_NORM;
        const float ax = vx / den, ay = vy / den, az = vz / den;
        const float b  = ax*ccx + ay*ccy + az*ccz;   // b = sum(a * closest)
        if (tid == 0) {
            const size_t oa = ((size_t)k * M + m) * 3;
            out_a[oa+0] = ax; out_a[oa+1] = ay; out_a[oa+2] = az;
            out_b[(size_t)k * M + m] = b;
            planes[4*k+0] = ax; planes[4*k+1] = ay;
            planes[4*k+2] = az; planes[4*k+3] = b;
        }
        ++k;
        if (k == MAX_ITERS) return;                  // all waves together
        scanN(ncount, ax, ay, az, b);
        ncount = ibc[1];
        ccx = fbc[0]; ccy = fbc[1]; ccz = fbc[2];
    }

    // ---- SOLO mode: waves 1-15 park at the command barrier ----
    if (wv != 0) {
        for (;;) {
            __syncthreads();
            const int c = ibc[3];
            if (c == CMD_EXIT) return;
            refillAll(SOLO_CAP);                     // CMD_REFILL
        }
    }
    // wave 0:
    int scount = ncount;
    for (;;) {
        if (scount == 0) {
            if (lane == 0) { ibc[3] = CMD_REFILL; ibc[5] = k; }
            __syncthreads();
            int st = refillAll(SOLO_CAP);
            if (st != ST_ALIVE) {
                if (lane == 0) ibc[3] = CMD_EXIT;
                __syncthreads();
                return;
            }
            k = ibc[5]; scount = ibc[1];
            ccx = fbc[0]; ccy = fbc[1]; ccz = fbc[2];
        }
        const float vx = ccx - tx, vy = ccy - ty, vz = ccz - tz;
        const float nrm = sqrtf(vx*vx + vy*vy + vz*vz);
        const float den = nrm + EPS_NORM;
        const float ax = vx / den, ay = vy / den, az = vz / den;
        const float b  = ax*ccx + ay*ccy + az*ccz;
        if (lane == 0) {
            const size_t oa = ((size_t)k * M + m) * 3;
            out_a[oa+0] = ax; out_a[oa+1] = ay; out_a[oa+2] = az;
            out_b[(size_t)k * M + m] = b;
            planes[4*k+0] = ax; planes[4*k+1] = ay;
            planes[4*k+2] = az; planes[4*k+3] = b;
        }
        ++k;
        if (k == MAX_ITERS) {
            if (lane == 0) ibc[3] = CMD_EXIT;
            __syncthreads();
            return;
        }
        {   // wave-synchronous in-place cut of the SoA (R10-proven)
            float dmin = INFINITY; int imin = 0;
            float mx = 0.f, my = 0.f, mz = 0.f;
            int wcur = 0;
            const int old = scount;
            for (int g0 = 0; g0 < old; g0 += 256) {
                float X[4], Y[4], Z[4], D[4]; int J[4];
                uint32_t km = 0;
                #pragma unroll
                for (int u = 0; u < 4; ++u) {        // read group fully first
                    const int e = g0 + u * 64 + lane;
                    if (e < old) {
                        X[u] = sx[e]; Y[u] = sy[e]; Z[u] = sz[e]; J[u] = sid[e];
                        float dt = ax*X[u] + ay*Y[u] + az*Z[u] - b;
                        if (dt < EPS_SEP) {
                            km |= (1u << u);
                            float p2 = X[u]*X[u] + Y[u]*Y[u] + Z[u]*Z[u];
                            float tp = tx*X[u] + ty*Y[u] + tz*Z[u];
                            D[u] = t2 + p2 - 2.0f*tp;
                        }
                    }
                }
                #pragma unroll
                for (int u = 0; u < 4; ++u) {        // compacted writes after
                    unsigned long long bal = __ballot(((km >> u) & 1u) != 0u);
                    int pos = wcur + (int)__popcll(bal & ((1ull << lane) - 1ull));
                    if ((km >> u) & 1u) {
                        sx[pos] = X[u]; sy[pos] = Y[u]; sz[pos] = Z[u]; sid[pos] = J[u];
                        if (D[u] < dmin || (D[u] == dmin && J[u] < imin)) {
                            dmin = D[u]; imin = J[u]; mx = X[u]; my = Y[u]; mz = Z[u];
                        }
                    }
                    wcur += (int)__popcll(bal);
                }   // writes stay < wcur <= g0+256 = next group's start
            }
            #pragma unroll
            for (int off = 32; off > 0; off >>= 1) {
                float od = __shfl_down(dmin, off, 64);
                int   oi = __shfl_down(imin, off, 64);
                float ox = __shfl_down(mx, off, 64);
                float oy = __shfl_down(my, off, 64);
                float oz = __shfl_down(mz, off, 64);
                if (od < dmin || (od == dmin && oi < imin)) {
                    dmin = od; imin = oi; mx = ox; my = oy; mz = oz;
                }
            }
            ccx = __shfl(mx, 0, 64);
            ccy = __shfl(my, 0, 64);
            ccz = __shfl(mz, 0, 64);
            scount = wcur;                           // uniform across lanes
        }
    }
}

extern "C" void kernel_launch(void* const* d_in, const int* in_sizes, int n_in,
                              void* d_out, int out_size, void* d_ws, size_t ws_size,
                              hipStream_t stream) {
    const float* pc = (const float*)d_in[0];
    const float* tg = (const float*)d_in[1];
    float* out = (float*)d_out;
    const int N = in_sizes[0] / 3;
    const int M = in_sizes[1] / 3;
    const int stepsA = (N + BLOCK * PT - 1) / (BLOCK * PT);

    // stored d2-prefix in ws: per block HB ints (prefix/cursors) + WARR ints
    // (indices). Degrade gracefully if ws is too small (WARR=0 -> fallback
    // refills only, still exact).
    long availPerBlock = (long)(ws_size / 4 / (size_t)(M > 0 ? M : 1)) - HB;
    int WARR = 0;
    if (availPerBlock >= 4096)
        WARR = (int)(availPerBlock < WARR_MAX ? availPerBlock : WARR_MAX);

    const size_t words = (size_t)4 * NEAR_CAP        // SoA
                       + 52 * 4                      // padded planes
                       + 4 * NW + NW + NW            // red_* , red_i, wsum
                       + 12 + 3 + 1;                 // ibc, fbc, cur
    const size_t smem = words * 4;                   // ~153 KB
    hipFuncSetAttribute((const void*)convex_plane_kernel,
                        hipFuncAttributeMaxDynamicSharedMemorySize, (int)smem);
    convex_plane_kernel<<<M, BLOCK, smem, stream>>>(pc, tg, out, N, M, stepsA,
                                                    (int*)d_ws, WARR);
}